// Round 3
// baseline (2715.044 us; speedup 1.0000x reference)
//
#include <hip/hip_runtime.h>
#include <hip/hip_bf16.h>
#include <stdint.h>

// B=8, S=200, H=256, V=32000, T=51. out = (8,50,64000) fp32 + scalar loss.

#define DEVI __device__ __forceinline__
#define AT_RLX __ATOMIC_RELAXED
#define SC_AGT __HIP_MEMORY_SCOPE_AGENT

// ---------------- ws layout (float offsets) ----------------
static constexpr size_t OFF_ACC   = 0;        // 4: nll_sum, valid_sum, bce_sum, m_sum
static constexpr size_t OFF_FLAGE = 4;        // 32 ints (encoder flags, unused now)
static constexpr size_t OFF_FLAGD = 36;       // 32 ints (decoder flags)
static constexpr size_t ZERO_FLOATS = 200;
static constexpr size_t OFF_CTX   = 256;      // 8*512 ctx accumulators
static constexpr size_t OFF_EMB   = 4352;     // [t][b][h] 200*8*256 (reused as HSEL)
static constexpr size_t OFF_HSEL  = OFF_EMB;
// Packed (gen<<32|h) exchange buffer for the encoder. Lives in the OFF_EMB
// region, which is dead between the ih-GEMMs (read emb) and the sel-GEMM
// (writes HSEL): 2 parities x 2 dirs x 2048 u64 = 64 KB.
static constexpr size_t OFF_HP    = OFF_EMB;
static constexpr size_t OFF_PREF  = OFF_EMB  + 409600;
static constexpr size_t OFF_PREB  = OFF_PREF + 1638400;
static constexpr size_t OFF_BIAS  = OFF_PREB + 1638400;  // 3072
static constexpr size_t OFF_HB    = OFF_BIAS + 3072;     // (unused, kept for layout)
static constexpr size_t OFF_HFIN  = OFF_HB   + 8192;     // 4096
static constexpr size_t OFF_CFIN  = OFF_HFIN + 4096;     // 4096
static constexpr size_t OFF_ENCOUT= OFF_CFIN + 4096;     // [b][s][512] = 819200
static constexpr size_t OFF_MASK  = OFF_ENCOUT + 819200; // 1600
static constexpr size_t OFF_C0    = OFF_MASK + 1600;     // 2048
static constexpr size_t OFF_EP    = OFF_C0   + 2048;     // [b][s][256] = 409600
static constexpr size_t OFF_WCP   = OFF_EP   + 409600;   // 256
static constexpr size_t OFF_BCP   = OFF_WCP  + 256;      // 256
static constexpr size_t OFF_DEMB  = OFF_BCP  + 256;      // 102400
static constexpr size_t OFF_DPRE  = OFF_DEMB + 102400;   // 409600
static constexpr size_t OFF_HBUF  = OFF_DPRE + 409600;   // dec h dbl buf [2][2048]
static constexpr size_t OFF_CS    = OFF_HBUF + 4096;     // 204800
static constexpr size_t OFF_HS    = OFF_CS   + 204800;   // 102400
static constexpr size_t OFF_AS    = OFF_HS   + 102400;   // 80000
static constexpr size_t OFF_PG    = OFF_AS   + 80000;    // 400 (pad 512)
static constexpr size_t OFF_PE    = OFF_PG   + 512;      // pe [sq][b][200] = 6400

// ---------------- helpers ----------------
DEVI float sigf(float x)      { return 1.0f / (1.0f + __expf(-x)); }
DEVI float tanh_fast(float x) { return 1.0f - 2.0f / (1.0f + __expf(2.0f * x)); }
DEVI float ald(const float* p)  { return __hip_atomic_load((float*)p, AT_RLX, SC_AGT); }
DEVI void  ast(float* p, float v){ __hip_atomic_store(p, v, AT_RLX, SC_AGT); }

// Distributed flag barrier (decoder only).
DEVI void fbar(int* flags, int g, int n, int val) {
  __syncthreads();
  if ((int)threadIdx.x == 0)
    __hip_atomic_store(flags + g, val, AT_RLX, SC_AGT);
  if ((int)threadIdx.x < n && (int)threadIdx.x != g) {
    while (__hip_atomic_load(flags + threadIdx.x, AT_RLX, SC_AGT) < val)
      __builtin_amdgcn_s_sleep(1);
  }
  __syncthreads();
}

// ---------------- small prep kernels ----------------
__global__ __launch_bounds__(256) void k_biassum(
    const float* bih_f, const float* bhh_f, const float* bih_b, const float* bhh_b,
    const float* bih_d, const float* bhh_d, float* ws) {
  int i = blockIdx.x * 256 + threadIdx.x;
  int which = i >> 10, jj = i & 1023;
  float v = (which == 0) ? bih_f[jj] + bhh_f[jj]
          : (which == 1) ? bih_b[jj] + bhh_b[jj]
                         : bih_d[jj] + bhh_d[jj];
  ws[OFF_BIAS + i] = v;
}

__global__ __launch_bounds__(256) void k_embed(
    const int* xin, const int* labels, const float* emb_enc, const float* emb_dec, float* ws) {
  int r = blockIdx.x, h = threadIdx.x;
  if (r < 1600) {
    int t = r >> 3, b = r & 7;
    ws[OFF_EMB + (size_t)r * 256 + h] = emb_enc[(size_t)xin[b * 200 + t] * 256 + h];
  } else {
    int r2 = r - 1600;
    int t = r2 >> 3, b = r2 & 7;
    int tok = (t == 0) ? 1 : labels[b * 51 + t];
    ws[OFF_DEMB + (size_t)r2 * 256 + h] = emb_dec[(size_t)tok * 256 + h];
  }
}

// ---------------- tiled SGEMM: C[m][n] = act(sum_k A[m][k]*B[n][k] + bias[n]) ----------------
template<int BM, int BN, int TM, int TN, int CMAP, int ACT, int AMAP>
__global__ __launch_bounds__(256) void k_gemm(
    const float* __restrict__ A, const float* __restrict__ B,
    const float* __restrict__ bias, float* __restrict__ C,
    int M, int K, int ldb, int ldc) {
  __shared__ float As[16][BM];
  __shared__ float Bs[16][BN];
  const int tid = threadIdx.x;
  const int tx = tid & 15, ty = tid >> 4;
  const int m0 = blockIdx.x * BM, n0 = blockIdx.y * BN;
  float acc[TM][TN];
#pragma unroll
  for (int i = 0; i < TM; ++i)
#pragma unroll
    for (int q = 0; q < TN; ++q) acc[i][q] = 0.f;

  for (int kk = 0; kk < K; kk += 16) {
#pragma unroll
    for (int e = tid; e < BM * 4; e += 256) {
      int m = e >> 2, k4 = (e & 3) * 4;
      int gm0 = m0 + m;
      float4 v = {0.f, 0.f, 0.f, 0.f};
      if (gm0 < M) {
        int gm = AMAP ? (((199 - (gm0 >> 3)) << 3) + (gm0 & 7)) : gm0;
        v = *(const float4*)(A + (size_t)gm * K + kk + k4);
      }
      As[k4 + 0][m] = v.x; As[k4 + 1][m] = v.y; As[k4 + 2][m] = v.z; As[k4 + 3][m] = v.w;
    }
#pragma unroll
    for (int e = tid; e < BN * 4; e += 256) {
      int n = e >> 2, k4 = (e & 3) * 4;
      float4 v = *(const float4*)(B + (size_t)(n0 + n) * ldb + kk + k4);
      Bs[k4 + 0][n] = v.x; Bs[k4 + 1][n] = v.y; Bs[k4 + 2][n] = v.z; Bs[k4 + 3][n] = v.w;
    }
    __syncthreads();
#pragma unroll
    for (int k = 0; k < 16; ++k) {
      float a[TM], bv[TN];
#pragma unroll
      for (int i = 0; i < TM; ++i) a[i] = As[k][ty * TM + i];
#pragma unroll
      for (int q = 0; q < TN; ++q) bv[q] = Bs[k][tx * TN + q];
#pragma unroll
      for (int i = 0; i < TM; ++i)
#pragma unroll
        for (int q = 0; q < TN; ++q) acc[i][q] += a[i] * bv[q];
    }
    __syncthreads();
  }
#pragma unroll
  for (int i = 0; i < TM; ++i) {
    int gm = m0 + ty * TM + i;
    if (gm >= M) continue;
    size_t base;
    if (CMAP == 1) { int t = gm >> 3, b = gm & 7; base = (size_t)(b * 50 + t) * 64000; }
    else            base = (size_t)gm * ldc;
#pragma unroll
    for (int q = 0; q < TN; ++q) {
      int n = n0 + tx * TN + q;
      float v = acc[i][q] + bias[n];
      if (ACT == 1) v = tanh_fast(v);
      C[base + n] = v;
    }
  }
}

// ---------------- encoder: 16 blocks, BOTH directions per block ----------------
// The fwd and bwd chains are independent; interleaving them in one block hides
// each direction's per-step stall chain (store visibility, poll detection,
// barrier vmcnt drains) behind the other direction's compute. Exchange is the
// gen-tagged (gen<<32|bits) u64 publish/spin from R1, per (parity, dir) region.
__global__ __launch_bounds__(512, 1) void k_encoder(
    const float* __restrict__ whh_f, const float* __restrict__ whh_b, float* __restrict__ ws) {
  __shared__ float hs[8 * 288];
  __shared__ float zs[512];
  const int p   = blockIdx.x;       // 0..15
  const int u0  = p * 16;
  unsigned long long* hp = (unsigned long long*)(ws + OFF_HP);
  const int tid = threadIdx.x;
  const int r = tid >> 3, kc = tid & 7;
  const int gt = r >> 4, ui = r & 15;
  const int j = gt * 256 + u0 + ui;
  float4 Wf[8], Wb[8];
  {
    const float* wrf = whh_f + (size_t)j * 256 + kc * 32;
    const float* wrb = whh_b + (size_t)j * 256 + kc * 32;
#pragma unroll
    for (int q = 0; q < 8; ++q) { Wf[q] = *(const float4*)(wrf + q * 4);
                                  Wb[q] = *(const float4*)(wrb + q * 4); }
  }
  const int ui2 = tid & 15, b2 = tid >> 4;
  float c_f = 0.f, c_b = 0.f;
  float* enc = ws + OFF_ENCOUT;

  for (int t = 0; t < 200; ++t) {
    // Prefetch both directions' pre-activations before any waiting.
    float pre_f = (ws + OFF_PREF)[((size_t)t * 8 + kc) * 1024 + j];
    float pre_b = (ws + OFF_PREB)[((size_t)t * 8 + kc) * 1024 + j];

    auto phase = [&](int dir, const float4* W, float pre_v, float& c_reg) {
      float acc[8];
#pragma unroll
      for (int b = 0; b < 8; ++b) acc[b] = 0.f;
      if (t > 0) {
        unsigned long long* src = hp + (size_t)((((t + 1) & 1) * 2 + dir) * 2048) + tid * 4;
        const unsigned long long e = (unsigned long long)(unsigned)t;
        unsigned long long a0, a1, a2, a3;
        for (;;) {
          a0 = __hip_atomic_load(src + 0, AT_RLX, SC_AGT);
          a1 = __hip_atomic_load(src + 1, AT_RLX, SC_AGT);
          a2 = __hip_atomic_load(src + 2, AT_RLX, SC_AGT);
          a3 = __hip_atomic_load(src + 3, AT_RLX, SC_AGT);
          if (((a0 >> 32) == e) && ((a1 >> 32) == e) &&
              ((a2 >> 32) == e) && ((a3 >> 32) == e)) break;
          __builtin_amdgcn_s_sleep(1);
        }
        int kk0 = (tid * 4) & 255, bb = tid >> 6;
        float* dst = &hs[bb * 288 + (kk0 >> 5) * 36 + (kk0 & 31)];
        dst[0] = __uint_as_float((unsigned)a0);
        dst[1] = __uint_as_float((unsigned)a1);
        dst[2] = __uint_as_float((unsigned)a2);
        dst[3] = __uint_as_float((unsigned)a3);
      }
      // Always-sync: orders hs writes before reads, and (at t==0) protects zs
      // from the previous phase's cell still reading it.
      __syncthreads();
      if (t > 0) {
        const float* hrow = &hs[kc * 36];
#pragma unroll
        for (int b = 0; b < 8; ++b) {
          const float* hbp = hrow + b * 288;
#pragma unroll
          for (int q = 0; q < 8; ++q) {
            float4 h4 = *(const float4*)(hbp + q * 4);
            acc[b] = fmaf(W[q].x, h4.x, acc[b]);
            acc[b] = fmaf(W[q].y, h4.y, acc[b]);
            acc[b] = fmaf(W[q].z, h4.z, acc[b]);
            acc[b] = fmaf(W[q].w, h4.w, acc[b]);
          }
        }
      }
      {
        bool h4b = (kc & 4) != 0;
#pragma unroll
        for (int i = 0; i < 4; ++i) {
          float send = h4b ? acc[i] : acc[i + 4];
          float keep = h4b ? acc[i + 4] : acc[i];
          acc[i] = keep + __shfl_xor(send, 4);
        }
        bool h2b = (kc & 2) != 0;
#pragma unroll
        for (int i = 0; i < 2; ++i) {
          float send = h2b ? acc[i] : acc[i + 2];
          float keep = h2b ? acc[i + 2] : acc[i];
          acc[i] = keep + __shfl_xor(send, 2);
        }
        bool h1b = (kc & 1) != 0;
        {
          float send = h1b ? acc[0] : acc[1];
          float keep = h1b ? acc[1] : acc[0];
          acc[0] = keep + __shfl_xor(send, 1);
        }
      }
      zs[tid] = acc[0] + pre_v;
      __syncthreads();
      if (tid < 128) {
        int i0 = ui2 * 8 + b2;
        float zi = zs[i0], zf = zs[128 + i0], zg = zs[256 + i0], zo = zs[384 + i0];
        float cn = sigf(zf) * c_reg + sigf(zi) * tanh_fast(zg);
        float hn = sigf(zo) * tanh_fast(cn);
        c_reg = cn;
        int uu = u0 + ui2;
        if (t < 199) {
          unsigned long long pk =
              ((unsigned long long)(unsigned)(t + 1) << 32) |
              (unsigned long long)__float_as_uint(hn);
          __hip_atomic_store(hp + (size_t)(((t & 1) * 2 + dir) * 2048) + b2 * 256 + uu,
                             pk, AT_RLX, SC_AGT);
        }
        int s = dir ? (199 - t) : t;
        enc[((size_t)b2 * 200 + s) * 512 + dir * 256 + uu] = hn;
        if (t == 199) {
          ws[OFF_HFIN + (size_t)(dir * 8 + b2) * 256 + uu] = hn;
          ws[OFF_CFIN + (size_t)(dir * 8 + b2) * 256 + uu] = cn;
        }
      }
      // No trailing barrier: the next phase's always-sync orders hs/zs reuse.
    };

    phase(0, Wf, pre_f, c_f);
    phase(1, Wb, pre_b, c_b);
  }
}

// ---------------- copy-prob head + BCE ----------------
__global__ __launch_bounds__(64) void k_selbce(
    const float* w_sel2, const float* b_sel2, const int* xin, float* ws) {
  int r = blockIdx.x, lane = threadIdx.x;
  float pacc = 0.f;
#pragma unroll
  for (int i = 0; i < 4; ++i) {
    int k = lane + 64 * i;
    pacc += ws[OFF_HSEL + (size_t)r * 256 + k] * w_sel2[k];
  }
#pragma unroll
  for (int m = 1; m < 64; m <<= 1) pacc += __shfl_xor(pacc, m);
  if (lane == 0) {
    float cp = sigf(pacc + b_sel2[0]);
    ws[OFF_MASK + r] = (cp > 1e-8f) ? 1.f : 0.f;
    int b = r / 200, s = r % 200;
    float m = (xin[b * 200 + s] != 0) ? 1.f : 0.f;
    if (m > 0.f) {
      float lp = fmaxf(logf(cp), -100.f);
      atomicAdd(ws + OFF_ACC + 2, -lp);
    }
    atomicAdd(ws + OFF_ACC + 3, m);
  }
}

__global__ __launch_bounds__(256) void k_wcp(
    const float* w_attn, const float* w_cov, const float* b_cov, float* ws) {
  int jj = threadIdx.x;
  float a = 0.f, c = 0.f;
  for (int h = 0; h < 256; ++h) {
    float w = w_attn[(size_t)jj * 1024 + 768 + h];
    a += w * w_cov[h];
    c += w * b_cov[h];
  }
  ws[OFF_WCP + jj] = a;
  ws[OFF_BCP + jj] = c;
}

__global__ __launch_bounds__(256) void k_h0c0(
    const float* w_rh, const float* b_rh, const float* w_rc, const float* b_rc, float* ws) {
  int b = blockIdx.x, jj = threadIdx.x;
  const float* hf  = ws + OFF_HFIN + (size_t)b * 256;
  const float* hbk = ws + OFF_HFIN + 2048 + (size_t)b * 256;
  const float* cf  = ws + OFF_CFIN + (size_t)b * 256;
  const float* cbk = ws + OFF_CFIN + 2048 + (size_t)b * 256;
  float ah = b_rh[jj], ac = b_rc[jj];
  for (int k = 0; k < 256; ++k) {
    ah += hf[k] * w_rh[(size_t)jj * 512 + k];
    ac += cf[k] * w_rc[(size_t)jj * 512 + k];
  }
  for (int k = 0; k < 256; ++k) {
    ah += hbk[k] * w_rh[(size_t)jj * 512 + 256 + k];
    ac += cbk[k] * w_rc[(size_t)jj * 512 + 256 + k];
  }
  ws[OFF_C0 + (size_t)b * 256 + jj] = fmaxf(ac, 0.f);
  ws[OFF_HBUF + (size_t)b * 256 + jj] = fmaxf(ah, 0.f);   // dec h buf0
}

// ---------------- decoder: 32 blocks, jj-separable attention, h-only exchange ----------------
__global__ __launch_bounds__(512, 1) void k_decoder(
    const float* __restrict__ wih_d, const float* __restrict__ whh_d,
    const float* __restrict__ w_attn, const float* __restrict__ w_attn_v,
    float* __restrict__ ws) {
  __shared__ float hc_s[8 * 768];     // [b][ctx512 | h256]
  __shared__ float h_pad[264];        // h[b1] staged, 32->33-pad chunks (36 stride)
  __shared__ float hw_q[64];          // hW quarter
  __shared__ float e_s[256];
  __shared__ float at_s[256], cv_s[256], msk_s[256];
  __shared__ float zs_l[256];
  __shared__ float wcq_s[64], bcq_s[64], wvq_s[64];
  __shared__ float mS_s[2];
  const int g = blockIdx.x, tid = threadIdx.x;
  const int b1 = g >> 2, sq = g & 3, s0 = sq * 50;
  int* flags = (int*)(ws + OFF_FLAGD);
  // hw role: jl = tid>>3 (jj within quarter), kq = tid&7 (k-chunk of 32)
  const int jl = tid >> 3, kq = tid & 7;
  // LSTM role (R3-proven): kseg in [0,16), row_l in [0,32)
  const int kseg = tid & 15, row_l = tid >> 4;
  const int u_l = row_l & 7, gate = row_l >> 3;
  const int j = gate * 256 + g * 8 + u_l;
  float4 W48[12];
#pragma unroll
  for (int q = 0; q < 12; ++q) {
    int k0 = 4 * kseg + 64 * q;
    W48[q] = (k0 < 512) ? *(const float4*)(wih_d + (size_t)j * 768 + 256 + k0)
                        : *(const float4*)(whh_d + (size_t)j * 256 + (k0 - 512));
  }
  // waT quarter: W32[q] = w_attn[sq*64+jl][512 + kq*32 + q*4 ..]
  float4 W32[8];
  {
    const float* wsrc = w_attn + (size_t)(sq * 64 + jl) * 1024 + 512 + kq * 32;
#pragma unroll
    for (int q = 0; q < 8; ++q) W32[q] = *(const float4*)(wsrc + q * 4);
  }
  // cell role: tid<64
  const int u_c = tid & 7, b_c = tid >> 3;
  float c_reg = (tid < 64) ? ws[OFF_C0 + (size_t)b_c * 256 + g * 8 + u_c] : 0.f;
  for (int s = tid; s < 256; s += 512) {
    msk_s[s] = (s < 200) ? ws[OFF_MASK + b1 * 200 + s] : 0.f;
    cv_s[s] = 0.f;
  }
  if (tid < 64) {
    wcq_s[tid] = ws[OFF_WCP + sq * 64 + tid];
    bcq_s[tid] = ws[OFF_BCP + sq * 64 + tid];
    wvq_s[tid] = w_attn_v[sq * 64 + tid];
  }
  __syncthreads();

  for (int t = 0; t < 50; ++t) {
    const int rb = t & 1, wb = 1 - rb;
    // ---- Phase B: zero ctx slice; stage h[b1]; hW quarter; partial scores pe ----
    if (tid < 128) ast(ws + OFF_CTX + g * 128 + tid, 0.f);
    if (tid < 256) {
      float v = ald(ws + OFF_HBUF + (size_t)rb * 2048 + b1 * 256 + tid);
      h_pad[(tid >> 5) * 33 + (tid & 31)] = v;
    }
    __syncthreads();
    {
      float a = 0.f;
      const float* hq = &h_pad[kq * 33];
#pragma unroll
      for (int q = 0; q < 8; ++q) {
        float4 h4 = { hq[q * 4 + 0], hq[q * 4 + 1], hq[q * 4 + 2], hq[q * 4 + 3] };
        a = fmaf(W32[q].x, h4.x, a);
        a = fmaf(W32[q].y, h4.y, a);
        a = fmaf(W32[q].z, h4.z, a);
        a = fmaf(W32[q].w, h4.w, a);
      }
      a += __shfl_xor(a, 1);
      a += __shfl_xor(a, 2);
      a += __shfl_xor(a, 4);
      if (kq == 0) hw_q[jl] = a;
    }
    __syncthreads();
    if (tid < 200) {
      const int s = tid;
      float cv = cv_s[s];
      const float* ep = ws + OFF_EP + ((size_t)(b1 * 200 + s)) * 256 + sq * 64;
      float pe = 0.f;
#pragma unroll
      for (int i4 = 0; i4 < 16; ++i4) {
        float4 e4 = *(const float4*)(ep + i4 * 4);
        float4 h4 = *(const float4*)(&hw_q[i4 * 4]);
        float4 w4 = *(const float4*)(&wcq_s[i4 * 4]);
        float4 b4 = *(const float4*)(&bcq_s[i4 * 4]);
        float4 v4 = *(const float4*)(&wvq_s[i4 * 4]);
        pe = fmaf(tanh_fast(e4.x + h4.x + cv * w4.x + b4.x), v4.x, pe);
        pe = fmaf(tanh_fast(e4.y + h4.y + cv * w4.y + b4.y), v4.y, pe);
        pe = fmaf(tanh_fast(e4.z + h4.z + cv * w4.z + b4.z), v4.z, pe);
        pe = fmaf(tanh_fast(e4.w + h4.w + cv * w4.w + b4.w), v4.w, pe);
      }
      ast(ws + OFF_PE + (size_t)(sq * 8 + b1) * 200 + s, pe);
    }
    fbar(flags, g, 32, 3 * t + 1);

    // ---- Phase C: full scores, softmax (local, deterministic), attn, cov, ctx partial ----
    if (tid < 200) {
      float e0 = ald(ws + OFF_PE + (size_t)(0 * 8 + b1) * 200 + tid);
      float e1 = ald(ws + OFF_PE + (size_t)(1 * 8 + b1) * 200 + tid);
      float e2 = ald(ws + OFF_PE + (size_t)(2 * 8 + b1) * 200 + tid);
      float e3 = ald(ws + OFF_PE + (size_t)(3 * 8 + b1) * 200 + tid);
      e_s[tid] = (e0 + e1) + (e2 + e3);
    }
    __syncthreads();
    if (tid < 64) {
      float m = -1e30f;
#pragma unroll
      for (int i = 0; i < 4; ++i) {
        int s = tid + 64 * i;
        if (s < 200) m = fmaxf(m, e_s[s]);
      }
#pragma unroll
      for (int md = 1; md < 64; md <<= 1) m = fmaxf(m, __shfl_xor(m, md));
      float es = 0.f, ems = 0.f;
#pragma unroll
      for (int i = 0; i < 4; ++i) {
        int s = tid + 64 * i;
        if (s < 200) {
          float e = __expf(e_s[s] - m);
          es += e; ems += e * msk_s[s];
        }
      }
#pragma unroll
      for (int md = 1; md < 64; md <<= 1) { es += __shfl_xor(es, md); ems += __shfl_xor(ems, md); }
      if (tid == 0) { mS_s[0] = m; mS_s[1] = 1.0f / (ems + 1e-10f * es); }
    }
    __syncthreads();
    if (tid < 200) {
      float a = __expf(e_s[tid] - mS_s[0]) * msk_s[tid] * mS_s[1];
      at_s[tid] = a;
      cv_s[tid] += a;
      if (tid >= s0 && tid < s0 + 50)
        ws[OFF_AS + ((size_t)t * 8 + b1) * 200 + tid] = a;
    }
    __syncthreads();
    {
      float ca = 0.f;
      const float* ebase = ws + OFF_ENCOUT + ((size_t)(b1 * 200 + s0)) * 512 + tid;
#pragma unroll 10
      for (int s2 = 0; s2 < 50; ++s2)
        ca = fmaf(at_s[s0 + s2], ebase[(size_t)s2 * 512], ca);
      atomicAdd(ws + OFF_CTX + b1 * 512 + tid, ca);
    }
    fbar(flags, g, 32, 3 * t + 2);

    // ---- LSTM phase: stage hcat, gates (reg weights), cell, publish h ----
    for (int e = tid; e < 6144; e += 512) {
      int bb = e / 768, kk2 = e % 768;
      hc_s[e] = (kk2 < 512) ? ald(ws + OFF_CTX + bb * 512 + kk2)
                            : ald(ws + OFF_HBUF + (size_t)rb * 2048 + bb * 256 + (kk2 - 512));
    }
    __syncthreads();
    if (g < 8) ws[OFF_CS + ((size_t)t * 8 + g) * 512 + tid] = hc_s[g * 768 + tid];
    float acc[8];
#pragma unroll
    for (int b = 0; b < 8; ++b) acc[b] = 0.f;
#pragma unroll
    for (int q = 0; q < 12; ++q) {
      int k0 = 4 * kseg + 64 * q;
#pragma unroll
      for (int b = 0; b < 8; ++b) {
        float4 h4 = *(const float4*)(&hc_s[b * 768 + k0]);
        acc[b] = fmaf(W48[q].x, h4.x, acc[b]);
        acc[b] = fmaf(W48[q].y, h4.y, acc[b]);
        acc[b] = fmaf(W48[q].z, h4.z, acc[b]);
        acc[b] = fmaf(W48[q].w, h4.w, acc[b]);
      }
    }
    {
      bool h8 = (kseg & 8) != 0;
#pragma unroll
      for (int i = 0; i < 4; ++i) {
        float send = h8 ? acc[i] : acc[i + 4];
        float keep = h8 ? acc[i + 4] : acc[i];
        acc[i] = keep + __shfl_xor(send, 8);
      }
      bool h4b = (kseg & 4) != 0;
#pragma unroll
      for (int i = 0; i < 2; ++i) {
        float send = h4b ? acc[i] : acc[i + 2];
        float keep = h4b ? acc[i + 2] : acc[i];
        acc[i] = keep + __shfl_xor(send, 4);
      }
      bool h2b = (kseg & 2) != 0;
      {
        float send = h2b ? acc[0] : acc[1];
        float keep = h2b ? acc[1] : acc[0];
        acc[0] = keep + __shfl_xor(send, 2);
      }
      acc[0] += __shfl_xor(acc[0], 1);
    }
    {
      int bz = kseg >> 1;
      float z = acc[0] + ws[OFF_DPRE + ((size_t)t * 8 + bz) * 1024 + j];
      if ((kseg & 1) == 0) zs_l[row_l * 8 + bz] = z;
    }
    __syncthreads();
    if (tid < 64) {
      float zi = zs_l[(0  + u_c) * 8 + b_c];
      float zf = zs_l[(8  + u_c) * 8 + b_c];
      float zg = zs_l[(16 + u_c) * 8 + b_c];
      float zo = zs_l[(24 + u_c) * 8 + b_c];
      float cn = sigf(zf) * c_reg + sigf(zi) * tanh_fast(zg);
      float hn = sigf(zo) * tanh_fast(cn);
      c_reg = cn;
      ast(ws + OFF_HBUF + (size_t)wb * 2048 + b_c * 256 + g * 8 + u_c, hn);
      ws[OFF_HS + ((size_t)t * 8 + b_c) * 256 + g * 8 + u_c] = hn;
    }
    fbar(flags, g, 32, 3 * t + 3);
  }
}

__global__ __launch_bounds__(64) void k_pgen(const float* w_ptr, const float* b_ptr, float* ws) {
  int r = blockIdx.x, lane = threadIdx.x;
  float p = 0.f;
#pragma unroll
  for (int i = 0; i < 12; ++i) {
    int k = lane + 64 * i;
    float v = (k < 512) ? ws[OFF_CS + (size_t)r * 512 + k]
                        : ws[OFF_HS + (size_t)r * 256 + (k - 512)];
    p += v * w_ptr[k];
  }
#pragma unroll
  for (int m = 1; m < 64; m <<= 1) p += __shfl_xor(p, m);
  if (lane == 0) ws[OFF_PG + r] = sigf(p + b_ptr[0]);
}

// ---------------- fused vocab softmax + pointer scatter + CE loss ----------------
__global__ __launch_bounds__(256) void k_v2(const int* xin, const int* labels, float* ws, float* out) {
  __shared__ float redm[256], reds[256];
  __shared__ int xv[200];
  __shared__ float s1sh, corrsh;
  int r = blockIdx.x, tid = threadIdx.x;
  int tt = r >> 3, b = r & 7;
  float* row = out + (size_t)(b * 50 + tt) * 64000;
  for (int i = tid; i < 200; i += 256) xv[i] = xin[b * 200 + i];
  float m = -1e30f, s = 0.f;
  for (int i = tid; i < 32000; i += 256) {
    float z = row[i];
    float nm = fmaxf(m, z);
    s = s * __expf(m - nm) + __expf(z - nm);
    m = nm;
  }
  redm[tid] = m; reds[tid] = s;
  __syncthreads();
  for (int st = 128; st >= 1; st >>= 1) {
    if (tid < st) {
      float m2 = redm[tid + st], s2 = reds[tid + st];
      float M = fmaxf(redm[tid], m2);
      reds[tid] = reds[tid] * __expf(redm[tid] - M) + s2 * __expf(m2 - M);
      redm[tid] = M;
    }
    __syncthreads();
  }
  float mx = redm[0], sum = reds[0];
  float pg = ws[OFF_PG + r];
  __syncthreads();
  float s1 = 0.f;
  float inv = 1.0f / sum;
  for (int i = tid; i < 32000; i += 256) {
    float z = row[i];
    float d = pg * (__expf(z - mx) * inv);
    row[i] = d;
    s1 += __expf(d);
  }
  for (int i = 32000 + tid; i < 64000; i += 256) row[i] = 0.0f;
  reds[tid] = s1;
  __syncthreads();
  for (int st = 128; st >= 1; st >>= 1) { if (tid < st) reds[tid] += reds[tid + st]; __syncthreads(); }
  if (tid == 0) { s1sh = reds[0]; corrsh = 0.f; }
  __syncthreads();
  if (tid < 200) {
    int v = xv[tid];
    bool own = true;
    for (int s2 = 0; s2 < tid; ++s2) if (xv[s2] == v) { own = false; break; }
    if (own) {
      float delta = 0.f;
      for (int s2 = tid; s2 < 200; ++s2)
        if (xv[s2] == v) delta += ws[OFF_AS + (size_t)r * 200 + s2];
      delta *= (1.0f - pg);
      float base = row[v];
      row[v] = base + delta;
      atomicAdd(&corrsh, __expf(base + delta) - __expf(base));
    }
  }
  __syncthreads();
  if (tid == 0) {
    float lse = logf(s1sh + corrsh + 32000.0f);
    int tgt = labels[b * 51 + tt + 1];
    float dt = row[tgt];
    float valid = (tgt != 0) ? 1.f : 0.f;
    atomicAdd(ws + OFF_ACC + 0, valid * (lse - dt));
    atomicAdd(ws + OFF_ACC + 1, valid);
  }
}

__global__ void k_loss(float* ws, float* out, int out_size) {
  out[out_size - 1] = ws[OFF_ACC + 0] / ws[OFF_ACC + 1] + ws[OFF_ACC + 2] / ws[OFF_ACC + 3];
}

// ---------------- launch ----------------
extern "C" void kernel_launch(void* const* d_in, const int* in_sizes, int n_in,
                              void* d_out, int out_size, void* d_ws, size_t ws_size,
                              hipStream_t stream) {
  (void)in_sizes; (void)n_in; (void)ws_size;
  const int*   x       = (const int*)  d_in[0];
  const int*   labels  = (const int*)  d_in[1];
  const float* emb_enc = (const float*)d_in[3];
  const float* wih_f   = (const float*)d_in[4];
  const float* whh_f   = (const float*)d_in[5];
  const float* bih_f   = (const float*)d_in[6];
  const float* bhh_f   = (const float*)d_in[7];
  const float* wih_b   = (const float*)d_in[8];
  const float* whh_b   = (const float*)d_in[9];
  const float* bih_b   = (const float*)d_in[10];
  const float* bhh_b   = (const float*)d_in[11];
  const float* w_sel1  = (const float*)d_in[12];
  const float* b_sel1  = (const float*)d_in[13];
  const float* w_sel2  = (const float*)d_in[14];
  const float* b_sel2  = (const float*)d_in[15];
  const float* w_rh    = (const float*)d_in[16];
  const float* b_rh    = (const float*)d_in[17];
  const float* w_rc    = (const float*)d_in[18];
  const float* b_rc    = (const float*)d_in[19];
  const float* emb_dec = (const float*)d_in[20];
  const float* wih_d   = (const float*)d_in[21];
  const float* whh_d   = (const float*)d_in[22];
  const float* bih_d   = (const float*)d_in[23];
  const float* bhh_d   = (const float*)d_in[24];
  const float* w_attn  = (const float*)d_in[25];
  const float* b_attn  = (const float*)d_in[26];
  const float* w_attn_v= (const float*)d_in[27];
  const float* w_ptr   = (const float*)d_in[28];
  const float* b_ptr   = (const float*)d_in[29];
  const float* w_gen   = (const float*)d_in[30];
  const float* b_gen   = (const float*)d_in[31];
  const float* w_cov   = (const float*)d_in[32];
  const float* b_cov   = (const float*)d_in[33];
  float* ws  = (float*)d_ws;
  float* out = (float*)d_out;

  hipMemsetAsync(d_ws, 0, ZERO_FLOATS * 4, stream);
  k_biassum<<<12, 256, 0, stream>>>(bih_f, bhh_f, bih_b, bhh_b, bih_d, bhh_d, ws);
  k_embed<<<2000, 256, 0, stream>>>(x, labels, emb_enc, emb_dec, ws);
  k_gemm<64,64,4,4,0,0,0><<<dim3(25,16), 256, 0, stream>>>(ws+OFF_EMB,  wih_f, ws+OFF_BIAS,      ws+OFF_PREF, 1600, 256, 256, 1024);
  k_gemm<64,64,4,4,0,0,1><<<dim3(25,16), 256, 0, stream>>>(ws+OFF_EMB,  wih_b, ws+OFF_BIAS+1024, ws+OFF_PREB, 1600, 256, 256, 1024);
  k_gemm<64,64,4,4,0,0,0><<<dim3(7,16),  256, 0, stream>>>(ws+OFF_DEMB, wih_d, ws+OFF_BIAS+2048, ws+OFF_DPRE, 400,  256, 768, 1024);
  // Clear the gen-tagged h exchange buffer (kills stale tags across graph
  // replays). Must come after the two ih-GEMMs that read OFF_EMB.
  hipMemsetAsync((void*)(ws + OFF_HP), 0, (size_t)2 * 2 * 2048 * sizeof(unsigned long long), stream);
  k_encoder<<<16, 512, 0, stream>>>(whh_f, whh_b, ws);
  k_gemm<64,64,4,4,0,1,0><<<dim3(25,4),  256, 0, stream>>>(ws+OFF_ENCOUT, w_sel1, b_sel1, ws+OFF_HSEL, 1600, 512, 512, 256);
  k_selbce<<<1600, 64, 0, stream>>>(w_sel2, b_sel2, x, ws);
  k_gemm<64,64,4,4,0,0,0><<<dim3(25,4),  256, 0, stream>>>(ws+OFF_ENCOUT, w_attn, b_attn, ws+OFF_EP, 1600, 512, 1024, 256);
  k_wcp<<<1, 256, 0, stream>>>(w_attn, w_cov, b_cov, ws);
  k_h0c0<<<8, 256, 0, stream>>>(w_rh, b_rh, w_rc, b_rc, ws);
  k_decoder<<<32, 512, 0, stream>>>(wih_d, whh_d, w_attn, w_attn_v, ws);
  k_pgen<<<400, 64, 0, stream>>>(w_ptr, b_ptr, ws);
  k_gemm<128,128,8,8,1,0,0><<<dim3(4,250), 256, 0, stream>>>(ws+OFF_HS, w_gen, b_gen, out, 400, 256, 256, 64000);
  k_v2<<<400, 256, 0, stream>>>(x, labels, ws, out);
  k_loss<<<1, 1, 0, stream>>>(ws, out, out_size);
}

// Round 4
// 2073.279 us; speedup vs baseline: 1.3095x; 1.3095x over previous
//
#include <hip/hip_runtime.h>
#include <hip/hip_bf16.h>
#include <stdint.h>

// B=8, S=200, H=256, V=32000, T=51. out = (8,50,64000) fp32 + scalar loss.

#define DEVI __device__ __forceinline__
#define AT_RLX __ATOMIC_RELAXED
#define SC_AGT __HIP_MEMORY_SCOPE_AGENT

// ---------------- ws layout (float offsets) ----------------
static constexpr size_t OFF_ACC   = 0;        // 4: nll_sum, valid_sum, bce_sum, m_sum
static constexpr size_t OFF_FLAGE = 4;        // 32 ints (encoder flags, unused now)
static constexpr size_t OFF_FLAGD = 36;       // 32 ints (decoder flags)
static constexpr size_t ZERO_FLOATS = 200;
static constexpr size_t OFF_CTX   = 256;      // 8*512 ctx accumulators
static constexpr size_t OFF_EMB   = 4352;     // [t][b][h] 200*8*256 (reused as HSEL)
static constexpr size_t OFF_HSEL  = OFF_EMB;
// Packed (gen<<32|h) exchange buffer for the encoder. Lives in the OFF_EMB
// region, which is dead between the ih-GEMMs (read emb) and the sel-GEMM
// (writes HSEL): 2 parities x 2 dirs x 2048 u64 = 64 KB.
static constexpr size_t OFF_HP    = OFF_EMB;
static constexpr size_t OFF_PREF  = OFF_EMB  + 409600;
static constexpr size_t OFF_PREB  = OFF_PREF + 1638400;
static constexpr size_t OFF_BIAS  = OFF_PREB + 1638400;  // 3072
static constexpr size_t OFF_HB    = OFF_BIAS + 3072;     // (unused, kept for layout)
static constexpr size_t OFF_HFIN  = OFF_HB   + 8192;     // 4096
static constexpr size_t OFF_CFIN  = OFF_HFIN + 4096;     // 4096
static constexpr size_t OFF_ENCOUT= OFF_CFIN + 4096;     // [b][s][512] = 819200
static constexpr size_t OFF_MASK  = OFF_ENCOUT + 819200; // 1600
static constexpr size_t OFF_C0    = OFF_MASK + 1600;     // 2048
static constexpr size_t OFF_EP    = OFF_C0   + 2048;     // [b][s][256] = 409600
static constexpr size_t OFF_WCP   = OFF_EP   + 409600;   // 256
static constexpr size_t OFF_BCP   = OFF_WCP  + 256;      // 256
static constexpr size_t OFF_DEMB  = OFF_BCP  + 256;      // 102400
static constexpr size_t OFF_DPRE  = OFF_DEMB + 102400;   // 409600
static constexpr size_t OFF_HBUF  = OFF_DPRE + 409600;   // dec h dbl buf [2][2048]
static constexpr size_t OFF_CS    = OFF_HBUF + 4096;     // 204800
static constexpr size_t OFF_HS    = OFF_CS   + 204800;   // 102400
static constexpr size_t OFF_AS    = OFF_HS   + 102400;   // 80000
static constexpr size_t OFF_PG    = OFF_AS   + 80000;    // 400 (pad 512)
static constexpr size_t OFF_PE    = OFF_PG   + 512;      // pe [sq][b][200] = 6400

// ---------------- helpers ----------------
DEVI float sigf(float x)      { return 1.0f / (1.0f + __expf(-x)); }
DEVI float tanh_fast(float x) { return 1.0f - 2.0f / (1.0f + __expf(2.0f * x)); }
DEVI float ald(const float* p)  { return __hip_atomic_load((float*)p, AT_RLX, SC_AGT); }
DEVI void  ast(float* p, float v){ __hip_atomic_store(p, v, AT_RLX, SC_AGT); }

// Distributed flag barrier (decoder only).
DEVI void fbar(int* flags, int g, int n, int val) {
  __syncthreads();
  if ((int)threadIdx.x == 0)
    __hip_atomic_store(flags + g, val, AT_RLX, SC_AGT);
  if ((int)threadIdx.x < n && (int)threadIdx.x != g) {
    while (__hip_atomic_load(flags + threadIdx.x, AT_RLX, SC_AGT) < val)
      __builtin_amdgcn_s_sleep(1);
  }
  __syncthreads();
}

// ---------------- small prep kernels ----------------
__global__ __launch_bounds__(256) void k_biassum(
    const float* bih_f, const float* bhh_f, const float* bih_b, const float* bhh_b,
    const float* bih_d, const float* bhh_d, float* ws) {
  int i = blockIdx.x * 256 + threadIdx.x;
  int which = i >> 10, jj = i & 1023;
  float v = (which == 0) ? bih_f[jj] + bhh_f[jj]
          : (which == 1) ? bih_b[jj] + bhh_b[jj]
                         : bih_d[jj] + bhh_d[jj];
  ws[OFF_BIAS + i] = v;
}

__global__ __launch_bounds__(256) void k_embed(
    const int* xin, const int* labels, const float* emb_enc, const float* emb_dec, float* ws) {
  int r = blockIdx.x, h = threadIdx.x;
  if (r < 1600) {
    int t = r >> 3, b = r & 7;
    ws[OFF_EMB + (size_t)r * 256 + h] = emb_enc[(size_t)xin[b * 200 + t] * 256 + h];
  } else {
    int r2 = r - 1600;
    int t = r2 >> 3, b = r2 & 7;
    int tok = (t == 0) ? 1 : labels[b * 51 + t];
    ws[OFF_DEMB + (size_t)r2 * 256 + h] = emb_dec[(size_t)tok * 256 + h];
  }
}

// ---------------- tiled SGEMM: C[m][n] = act(sum_k A[m][k]*B[n][k] + bias[n]) ----------------
template<int BM, int BN, int TM, int TN, int CMAP, int ACT, int AMAP>
__global__ __launch_bounds__(256) void k_gemm(
    const float* __restrict__ A, const float* __restrict__ B,
    const float* __restrict__ bias, float* __restrict__ C,
    int M, int K, int ldb, int ldc) {
  __shared__ float As[16][BM];
  __shared__ float Bs[16][BN];
  const int tid = threadIdx.x;
  const int tx = tid & 15, ty = tid >> 4;
  const int m0 = blockIdx.x * BM, n0 = blockIdx.y * BN;
  float acc[TM][TN];
#pragma unroll
  for (int i = 0; i < TM; ++i)
#pragma unroll
    for (int q = 0; q < TN; ++q) acc[i][q] = 0.f;

  for (int kk = 0; kk < K; kk += 16) {
#pragma unroll
    for (int e = tid; e < BM * 4; e += 256) {
      int m = e >> 2, k4 = (e & 3) * 4;
      int gm0 = m0 + m;
      float4 v = {0.f, 0.f, 0.f, 0.f};
      if (gm0 < M) {
        int gm = AMAP ? (((199 - (gm0 >> 3)) << 3) + (gm0 & 7)) : gm0;
        v = *(const float4*)(A + (size_t)gm * K + kk + k4);
      }
      As[k4 + 0][m] = v.x; As[k4 + 1][m] = v.y; As[k4 + 2][m] = v.z; As[k4 + 3][m] = v.w;
    }
#pragma unroll
    for (int e = tid; e < BN * 4; e += 256) {
      int n = e >> 2, k4 = (e & 3) * 4;
      float4 v = *(const float4*)(B + (size_t)(n0 + n) * ldb + kk + k4);
      Bs[k4 + 0][n] = v.x; Bs[k4 + 1][n] = v.y; Bs[k4 + 2][n] = v.z; Bs[k4 + 3][n] = v.w;
    }
    __syncthreads();
#pragma unroll
    for (int k = 0; k < 16; ++k) {
      float a[TM], bv[TN];
#pragma unroll
      for (int i = 0; i < TM; ++i) a[i] = As[k][ty * TM + i];
#pragma unroll
      for (int q = 0; q < TN; ++q) bv[q] = Bs[k][tx * TN + q];
#pragma unroll
      for (int i = 0; i < TM; ++i)
#pragma unroll
        for (int q = 0; q < TN; ++q) acc[i][q] += a[i] * bv[q];
    }
    __syncthreads();
  }
#pragma unroll
  for (int i = 0; i < TM; ++i) {
    int gm = m0 + ty * TM + i;
    if (gm >= M) continue;
    size_t base;
    if (CMAP == 1) { int t = gm >> 3, b = gm & 7; base = (size_t)(b * 50 + t) * 64000; }
    else            base = (size_t)gm * ldc;
#pragma unroll
    for (int q = 0; q < TN; ++q) {
      int n = n0 + tx * TN + q;
      float v = acc[i][q] + bias[n];
      if (ACT == 1) v = tanh_fast(v);
      C[base + n] = v;
    }
  }
}

// ---------------- encoder: 32 blocks (16/dir), register-tiled matvec ----------------
// R3 post-mortem: per-step cost is LDS-issue-bound (512 ds_read_b128/step/CU).
// Fix: each thread computes 2 j-rows over a 16-wide k-slice (jt=2) -> 32 reads
// per thread instead of 64; h staged as [b][q][kc4] float4-interleaved so the
// staging write is one ds_write_b128 and reads are 256B-consecutive (2-way
// bank aliasing = free). Cross-block exchange: R1's gen-tagged u64 publish.
__global__ __launch_bounds__(512, 1) void k_encoder(
    const float* __restrict__ whh_f, const float* __restrict__ whh_b, float* __restrict__ ws) {
  __shared__ float hs2[2048];   // [b][q][kc4] float4-interleaved: b*256 + q*64 + kc4*4
  __shared__ float zs[512];
  const int dir = blockIdx.x >> 4;
  const int p   = blockIdx.x & 15;
  const int u0  = p * 16;
  const float* whh = dir ? whh_b : whh_f;
  const float* pre = ws + (dir ? OFF_PREB : OFF_PREF);
  unsigned long long* hp = (unsigned long long*)(ws + OFF_HP);
  const int tid = threadIdx.x;
  // matvec roles: kc4 = k-chunk of 16 (16 chunks cover 256); jp = j-pair index
  const int kc4 = tid & 15;
  const int jp  = tid >> 4;          // [0,32): handles jj = jp*2, jp*2+1
  const int jj0 = jp * 2, jj1 = jj0 + 1;
  const int jg0 = (jj0 >> 4) * 256 + u0 + (jj0 & 15);
  const int jg1 = (jj1 >> 4) * 256 + u0 + (jj1 & 15);
  float4 W0[4], W1[4];
  {
    const float* w0 = whh + (size_t)jg0 * 256 + kc4 * 16;
    const float* w1 = whh + (size_t)jg1 * 256 + kc4 * 16;
#pragma unroll
    for (int q = 0; q < 4; ++q) { W0[q] = *(const float4*)(w0 + q * 4);
                                  W1[q] = *(const float4*)(w1 + q * 4); }
  }
  // final-z role (after 16-lane reduce, lane kc4 holds (jl=kc4>>3, b=kc4&7))
  const int jlf = kc4 >> 3, bf = kc4 & 7;
  const int jjf = jp * 2 + jlf;
  const int jf  = (jjf >> 4) * 256 + u0 + (jjf & 15);
  const int zsl = (jjf >> 4) * 128 + (jjf & 15) * 8 + bf;
  // staging-write role: thread holds h elements [tid*4, tid*4+4)
  const int wb_ = tid >> 6;                 // b
  const int kk0 = (tid * 4) & 255;          // k of first element
  const int wdst = wb_ * 256 + ((kk0 >> 2) & 3) * 64 + (kk0 >> 4) * 4;
  // cell role (tid<128): ui2 = u within slice, b2 = batch
  const int ui2 = tid & 15, b2 = tid >> 4;
  float c_reg = 0.f;
  float* enc = ws + OFF_ENCOUT;

  for (int t = 0; t < 200; ++t) {
    float pre_v = pre[((size_t)t * 8 + bf) * 1024 + jf];
    float acc[16];
#pragma unroll
    for (int i = 0; i < 16; ++i) acc[i] = 0.f;
    if (t > 0) {
      unsigned long long* src = hp + (size_t)((((t + 1) & 1) * 2 + dir) * 2048) + tid * 4;
      const unsigned long long e = (unsigned long long)(unsigned)t;
      unsigned long long a0, a1, a2, a3;
      for (;;) {
        a0 = __hip_atomic_load(src + 0, AT_RLX, SC_AGT);
        a1 = __hip_atomic_load(src + 1, AT_RLX, SC_AGT);
        a2 = __hip_atomic_load(src + 2, AT_RLX, SC_AGT);
        a3 = __hip_atomic_load(src + 3, AT_RLX, SC_AGT);
        if (((a0 >> 32) == e) && ((a1 >> 32) == e) &&
            ((a2 >> 32) == e) && ((a3 >> 32) == e)) break;
        __builtin_amdgcn_s_sleep(1);
      }
      float4 hv;
      hv.x = __uint_as_float((unsigned)a0);
      hv.y = __uint_as_float((unsigned)a1);
      hv.z = __uint_as_float((unsigned)a2);
      hv.w = __uint_as_float((unsigned)a3);
      *(float4*)(&hs2[wdst]) = hv;
    }
    __syncthreads();
    if (t > 0) {
#pragma unroll
      for (int b = 0; b < 8; ++b) {
        const float* hb = &hs2[b * 256 + kc4 * 4];
#pragma unroll
        for (int q = 0; q < 4; ++q) {
          float4 h4 = *(const float4*)(hb + q * 64);
          acc[b]     = fmaf(W0[q].x, h4.x, acc[b]);
          acc[b]     = fmaf(W0[q].y, h4.y, acc[b]);
          acc[b]     = fmaf(W0[q].z, h4.z, acc[b]);
          acc[b]     = fmaf(W0[q].w, h4.w, acc[b]);
          acc[8 + b] = fmaf(W1[q].x, h4.x, acc[8 + b]);
          acc[8 + b] = fmaf(W1[q].y, h4.y, acc[8 + b]);
          acc[8 + b] = fmaf(W1[q].z, h4.z, acc[8 + b]);
          acc[8 + b] = fmaf(W1[q].w, h4.w, acc[8 + b]);
        }
      }
    }
    // 16-lane butterfly over kc4: final lane kc4 holds acc for (jl=kc4>>3, b=kc4&7)
    {
      bool h8 = (kc4 & 8) != 0;
#pragma unroll
      for (int i = 0; i < 8; ++i) {
        float send = h8 ? acc[i] : acc[i + 8];
        float keep = h8 ? acc[i + 8] : acc[i];
        acc[i] = keep + __shfl_xor(send, 8);
      }
      bool h4b = (kc4 & 4) != 0;
#pragma unroll
      for (int i = 0; i < 4; ++i) {
        float send = h4b ? acc[i] : acc[i + 4];
        float keep = h4b ? acc[i + 4] : acc[i];
        acc[i] = keep + __shfl_xor(send, 4);
      }
      bool h2b = (kc4 & 2) != 0;
#pragma unroll
      for (int i = 0; i < 2; ++i) {
        float send = h2b ? acc[i] : acc[i + 2];
        float keep = h2b ? acc[i + 2] : acc[i];
        acc[i] = keep + __shfl_xor(send, 2);
      }
      bool h1b = (kc4 & 1) != 0;
      {
        float send = h1b ? acc[0] : acc[1];
        float keep = h1b ? acc[1] : acc[0];
        acc[0] = keep + __shfl_xor(send, 1);
      }
    }
    zs[zsl] = acc[0] + pre_v;
    __syncthreads();
    if (tid < 128) {
      int i0 = ui2 * 8 + b2;
      float zi = zs[i0], zf = zs[128 + i0], zg = zs[256 + i0], zo = zs[384 + i0];
      float cn = sigf(zf) * c_reg + sigf(zi) * tanh_fast(zg);
      float hn = sigf(zo) * tanh_fast(cn);
      c_reg = cn;
      int uu = u0 + ui2;
      if (t < 199) {
        unsigned long long pk =
            ((unsigned long long)(unsigned)(t + 1) << 32) |
            (unsigned long long)__float_as_uint(hn);
        __hip_atomic_store(hp + (size_t)(((t & 1) * 2 + dir) * 2048) + b2 * 256 + uu,
                           pk, AT_RLX, SC_AGT);
      }
      int s = dir ? (199 - t) : t;
      enc[((size_t)b2 * 200 + s) * 512 + dir * 256 + uu] = hn;
      if (t == 199) {
        ws[OFF_HFIN + (size_t)(dir * 8 + b2) * 256 + uu] = hn;
        ws[OFF_CFIN + (size_t)(dir * 8 + b2) * 256 + uu] = cn;
      }
    }
    // No trailing barrier: next step's post-spin barrier orders hs2/zs reuse.
  }
}

// ---------------- copy-prob head + BCE ----------------
__global__ __launch_bounds__(64) void k_selbce(
    const float* w_sel2, const float* b_sel2, const int* xin, float* ws) {
  int r = blockIdx.x, lane = threadIdx.x;
  float pacc = 0.f;
#pragma unroll
  for (int i = 0; i < 4; ++i) {
    int k = lane + 64 * i;
    pacc += ws[OFF_HSEL + (size_t)r * 256 + k] * w_sel2[k];
  }
#pragma unroll
  for (int m = 1; m < 64; m <<= 1) pacc += __shfl_xor(pacc, m);
  if (lane == 0) {
    float cp = sigf(pacc + b_sel2[0]);
    ws[OFF_MASK + r] = (cp > 1e-8f) ? 1.f : 0.f;
    int b = r / 200, s = r % 200;
    float m = (xin[b * 200 + s] != 0) ? 1.f : 0.f;
    if (m > 0.f) {
      float lp = fmaxf(logf(cp), -100.f);
      atomicAdd(ws + OFF_ACC + 2, -lp);
    }
    atomicAdd(ws + OFF_ACC + 3, m);
  }
}

__global__ __launch_bounds__(256) void k_wcp(
    const float* w_attn, const float* w_cov, const float* b_cov, float* ws) {
  int jj = threadIdx.x;
  float a = 0.f, c = 0.f;
  for (int h = 0; h < 256; ++h) {
    float w = w_attn[(size_t)jj * 1024 + 768 + h];
    a += w * w_cov[h];
    c += w * b_cov[h];
  }
  ws[OFF_WCP + jj] = a;
  ws[OFF_BCP + jj] = c;
}

__global__ __launch_bounds__(256) void k_h0c0(
    const float* w_rh, const float* b_rh, const float* w_rc, const float* b_rc, float* ws) {
  int b = blockIdx.x, jj = threadIdx.x;
  const float* hf  = ws + OFF_HFIN + (size_t)b * 256;
  const float* hbk = ws + OFF_HFIN + 2048 + (size_t)b * 256;
  const float* cf  = ws + OFF_CFIN + (size_t)b * 256;
  const float* cbk = ws + OFF_CFIN + 2048 + (size_t)b * 256;
  float ah = b_rh[jj], ac = b_rc[jj];
  for (int k = 0; k < 256; ++k) {
    ah += hf[k] * w_rh[(size_t)jj * 512 + k];
    ac += cf[k] * w_rc[(size_t)jj * 512 + k];
  }
  for (int k = 0; k < 256; ++k) {
    ah += hbk[k] * w_rh[(size_t)jj * 512 + 256 + k];
    ac += cbk[k] * w_rc[(size_t)jj * 512 + 256 + k];
  }
  ws[OFF_C0 + (size_t)b * 256 + jj] = fmaxf(ac, 0.f);
  ws[OFF_HBUF + (size_t)b * 256 + jj] = fmaxf(ah, 0.f);   // dec h buf0
}

// ---------------- decoder: 32 blocks, jj-separable attention, h-only exchange ----------------
__global__ __launch_bounds__(512, 1) void k_decoder(
    const float* __restrict__ wih_d, const float* __restrict__ whh_d,
    const float* __restrict__ w_attn, const float* __restrict__ w_attn_v,
    float* __restrict__ ws) {
  __shared__ float hc_s[8 * 768];     // [b][ctx512 | h256]
  __shared__ float h_pad[264];        // h[b1] staged, 32->33-pad chunks (36 stride)
  __shared__ float hw_q[64];          // hW quarter
  __shared__ float e_s[256];
  __shared__ float at_s[256], cv_s[256], msk_s[256];
  __shared__ float zs_l[256];
  __shared__ float wcq_s[64], bcq_s[64], wvq_s[64];
  __shared__ float mS_s[2];
  const int g = blockIdx.x, tid = threadIdx.x;
  const int b1 = g >> 2, sq = g & 3, s0 = sq * 50;
  int* flags = (int*)(ws + OFF_FLAGD);
  // hw role: jl = tid>>3 (jj within quarter), kq = tid&7 (k-chunk of 32)
  const int jl = tid >> 3, kq = tid & 7;
  // LSTM role (R3-proven): kseg in [0,16), row_l in [0,32)
  const int kseg = tid & 15, row_l = tid >> 4;
  const int u_l = row_l & 7, gate = row_l >> 3;
  const int j = gate * 256 + g * 8 + u_l;
  float4 W48[12];
#pragma unroll
  for (int q = 0; q < 12; ++q) {
    int k0 = 4 * kseg + 64 * q;
    W48[q] = (k0 < 512) ? *(const float4*)(wih_d + (size_t)j * 768 + 256 + k0)
                        : *(const float4*)(whh_d + (size_t)j * 256 + (k0 - 512));
  }
  // waT quarter: W32[q] = w_attn[sq*64+jl][512 + kq*32 + q*4 ..]
  float4 W32[8];
  {
    const float* wsrc = w_attn + (size_t)(sq * 64 + jl) * 1024 + 512 + kq * 32;
#pragma unroll
    for (int q = 0; q < 8; ++q) W32[q] = *(const float4*)(wsrc + q * 4);
  }
  // cell role: tid<64
  const int u_c = tid & 7, b_c = tid >> 3;
  float c_reg = (tid < 64) ? ws[OFF_C0 + (size_t)b_c * 256 + g * 8 + u_c] : 0.f;
  for (int s = tid; s < 256; s += 512) {
    msk_s[s] = (s < 200) ? ws[OFF_MASK + b1 * 200 + s] : 0.f;
    cv_s[s] = 0.f;
  }
  if (tid < 64) {
    wcq_s[tid] = ws[OFF_WCP + sq * 64 + tid];
    bcq_s[tid] = ws[OFF_BCP + sq * 64 + tid];
    wvq_s[tid] = w_attn_v[sq * 64 + tid];
  }
  __syncthreads();

  for (int t = 0; t < 50; ++t) {
    const int rb = t & 1, wb = 1 - rb;
    // ---- Phase B: zero ctx slice; stage h[b1]; hW quarter; partial scores pe ----
    if (tid < 128) ast(ws + OFF_CTX + g * 128 + tid, 0.f);
    if (tid < 256) {
      float v = ald(ws + OFF_HBUF + (size_t)rb * 2048 + b1 * 256 + tid);
      h_pad[(tid >> 5) * 33 + (tid & 31)] = v;
    }
    __syncthreads();
    {
      float a = 0.f;
      const float* hq = &h_pad[kq * 33];
#pragma unroll
      for (int q = 0; q < 8; ++q) {
        float4 h4 = { hq[q * 4 + 0], hq[q * 4 + 1], hq[q * 4 + 2], hq[q * 4 + 3] };
        a = fmaf(W32[q].x, h4.x, a);
        a = fmaf(W32[q].y, h4.y, a);
        a = fmaf(W32[q].z, h4.z, a);
        a = fmaf(W32[q].w, h4.w, a);
      }
      a += __shfl_xor(a, 1);
      a += __shfl_xor(a, 2);
      a += __shfl_xor(a, 4);
      if (kq == 0) hw_q[jl] = a;
    }
    __syncthreads();
    if (tid < 200) {
      const int s = tid;
      float cv = cv_s[s];
      const float* ep = ws + OFF_EP + ((size_t)(b1 * 200 + s)) * 256 + sq * 64;
      float pe = 0.f;
#pragma unroll
      for (int i4 = 0; i4 < 16; ++i4) {
        float4 e4 = *(const float4*)(ep + i4 * 4);
        float4 h4 = *(const float4*)(&hw_q[i4 * 4]);
        float4 w4 = *(const float4*)(&wcq_s[i4 * 4]);
        float4 b4 = *(const float4*)(&bcq_s[i4 * 4]);
        float4 v4 = *(const float4*)(&wvq_s[i4 * 4]);
        pe = fmaf(tanh_fast(e4.x + h4.x + cv * w4.x + b4.x), v4.x, pe);
        pe = fmaf(tanh_fast(e4.y + h4.y + cv * w4.y + b4.y), v4.y, pe);
        pe = fmaf(tanh_fast(e4.z + h4.z + cv * w4.z + b4.z), v4.z, pe);
        pe = fmaf(tanh_fast(e4.w + h4.w + cv * w4.w + b4.w), v4.w, pe);
      }
      ast(ws + OFF_PE + (size_t)(sq * 8 + b1) * 200 + s, pe);
    }
    fbar(flags, g, 32, 3 * t + 1);

    // ---- Phase C: full scores, softmax (local, deterministic), attn, cov, ctx partial ----
    if (tid < 200) {
      float e0 = ald(ws + OFF_PE + (size_t)(0 * 8 + b1) * 200 + tid);
      float e1 = ald(ws + OFF_PE + (size_t)(1 * 8 + b1) * 200 + tid);
      float e2 = ald(ws + OFF_PE + (size_t)(2 * 8 + b1) * 200 + tid);
      float e3 = ald(ws + OFF_PE + (size_t)(3 * 8 + b1) * 200 + tid);
      e_s[tid] = (e0 + e1) + (e2 + e3);
    }
    __syncthreads();
    if (tid < 64) {
      float m = -1e30f;
#pragma unroll
      for (int i = 0; i < 4; ++i) {
        int s = tid + 64 * i;
        if (s < 200) m = fmaxf(m, e_s[s]);
      }
#pragma unroll
      for (int md = 1; md < 64; md <<= 1) m = fmaxf(m, __shfl_xor(m, md));
      float es = 0.f, ems = 0.f;
#pragma unroll
      for (int i = 0; i < 4; ++i) {
        int s = tid + 64 * i;
        if (s < 200) {
          float e = __expf(e_s[s] - m);
          es += e; ems += e * msk_s[s];
        }
      }
#pragma unroll
      for (int md = 1; md < 64; md <<= 1) { es += __shfl_xor(es, md); ems += __shfl_xor(ems, md); }
      if (tid == 0) { mS_s[0] = m; mS_s[1] = 1.0f / (ems + 1e-10f * es); }
    }
    __syncthreads();
    if (tid < 200) {
      float a = __expf(e_s[tid] - mS_s[0]) * msk_s[tid] * mS_s[1];
      at_s[tid] = a;
      cv_s[tid] += a;
      if (tid >= s0 && tid < s0 + 50)
        ws[OFF_AS + ((size_t)t * 8 + b1) * 200 + tid] = a;
    }
    __syncthreads();
    {
      float ca = 0.f;
      const float* ebase = ws + OFF_ENCOUT + ((size_t)(b1 * 200 + s0)) * 512 + tid;
#pragma unroll 10
      for (int s2 = 0; s2 < 50; ++s2)
        ca = fmaf(at_s[s0 + s2], ebase[(size_t)s2 * 512], ca);
      atomicAdd(ws + OFF_CTX + b1 * 512 + tid, ca);
    }
    fbar(flags, g, 32, 3 * t + 2);

    // ---- LSTM phase: stage hcat, gates (reg weights), cell, publish h ----
    for (int e = tid; e < 6144; e += 512) {
      int bb = e / 768, kk2 = e % 768;
      hc_s[e] = (kk2 < 512) ? ald(ws + OFF_CTX + bb * 512 + kk2)
                            : ald(ws + OFF_HBUF + (size_t)rb * 2048 + bb * 256 + (kk2 - 512));
    }
    __syncthreads();
    if (g < 8) ws[OFF_CS + ((size_t)t * 8 + g) * 512 + tid] = hc_s[g * 768 + tid];
    float acc[8];
#pragma unroll
    for (int b = 0; b < 8; ++b) acc[b] = 0.f;
#pragma unroll
    for (int q = 0; q < 12; ++q) {
      int k0 = 4 * kseg + 64 * q;
#pragma unroll
      for (int b = 0; b < 8; ++b) {
        float4 h4 = *(const float4*)(&hc_s[b * 768 + k0]);
        acc[b] = fmaf(W48[q].x, h4.x, acc[b]);
        acc[b] = fmaf(W48[q].y, h4.y, acc[b]);
        acc[b] = fmaf(W48[q].z, h4.z, acc[b]);
        acc[b] = fmaf(W48[q].w, h4.w, acc[b]);
      }
    }
    {
      bool h8 = (kseg & 8) != 0;
#pragma unroll
      for (int i = 0; i < 4; ++i) {
        float send = h8 ? acc[i] : acc[i + 4];
        float keep = h8 ? acc[i + 4] : acc[i];
        acc[i] = keep + __shfl_xor(send, 8);
      }
      bool h4b = (kseg & 4) != 0;
#pragma unroll
      for (int i = 0; i < 2; ++i) {
        float send = h4b ? acc[i] : acc[i + 2];
        float keep = h4b ? acc[i + 2] : acc[i];
        acc[i] = keep + __shfl_xor(send, 4);
      }
      bool h2b = (kseg & 2) != 0;
      {
        float send = h2b ? acc[0] : acc[1];
        float keep = h2b ? acc[1] : acc[0];
        acc[0] = keep + __shfl_xor(send, 2);
      }
      acc[0] += __shfl_xor(acc[0], 1);
    }
    {
      int bz = kseg >> 1;
      float z = acc[0] + ws[OFF_DPRE + ((size_t)t * 8 + bz) * 1024 + j];
      if ((kseg & 1) == 0) zs_l[row_l * 8 + bz] = z;
    }
    __syncthreads();
    if (tid < 64) {
      float zi = zs_l[(0  + u_c) * 8 + b_c];
      float zf = zs_l[(8  + u_c) * 8 + b_c];
      float zg = zs_l[(16 + u_c) * 8 + b_c];
      float zo = zs_l[(24 + u_c) * 8 + b_c];
      float cn = sigf(zf) * c_reg + sigf(zi) * tanh_fast(zg);
      float hn = sigf(zo) * tanh_fast(cn);
      c_reg = cn;
      ast(ws + OFF_HBUF + (size_t)wb * 2048 + b_c * 256 + g * 8 + u_c, hn);
      ws[OFF_HS + ((size_t)t * 8 + b_c) * 256 + g * 8 + u_c] = hn;
    }
    fbar(flags, g, 32, 3 * t + 3);
  }
}

__global__ __launch_bounds__(64) void k_pgen(const float* w_ptr, const float* b_ptr, float* ws) {
  int r = blockIdx.x, lane = threadIdx.x;
  float p = 0.f;
#pragma unroll
  for (int i = 0; i < 12; ++i) {
    int k = lane + 64 * i;
    float v = (k < 512) ? ws[OFF_CS + (size_t)r * 512 + k]
                        : ws[OFF_HS + (size_t)r * 256 + (k - 512)];
    p += v * w_ptr[k];
  }
#pragma unroll
  for (int m = 1; m < 64; m <<= 1) p += __shfl_xor(p, m);
  if (lane == 0) ws[OFF_PG + r] = sigf(p + b_ptr[0]);
}

// ---------------- fused vocab softmax + pointer scatter + CE loss ----------------
__global__ __launch_bounds__(256) void k_v2(const int* xin, const int* labels, float* ws, float* out) {
  __shared__ float redm[256], reds[256];
  __shared__ int xv[200];
  __shared__ float s1sh, corrsh;
  int r = blockIdx.x, tid = threadIdx.x;
  int tt = r >> 3, b = r & 7;
  float* row = out + (size_t)(b * 50 + tt) * 64000;
  for (int i = tid; i < 200; i += 256) xv[i] = xin[b * 200 + i];
  float m = -1e30f, s = 0.f;
  for (int i = tid; i < 32000; i += 256) {
    float z = row[i];
    float nm = fmaxf(m, z);
    s = s * __expf(m - nm) + __expf(z - nm);
    m = nm;
  }
  redm[tid] = m; reds[tid] = s;
  __syncthreads();
  for (int st = 128; st >= 1; st >>= 1) {
    if (tid < st) {
      float m2 = redm[tid + st], s2 = reds[tid + st];
      float M = fmaxf(redm[tid], m2);
      reds[tid] = reds[tid] * __expf(redm[tid] - M) + s2 * __expf(m2 - M);
      redm[tid] = M;
    }
    __syncthreads();
  }
  float mx = redm[0], sum = reds[0];
  float pg = ws[OFF_PG + r];
  __syncthreads();
  float s1 = 0.f;
  float inv = 1.0f / sum;
  for (int i = tid; i < 32000; i += 256) {
    float z = row[i];
    float d = pg * (__expf(z - mx) * inv);
    row[i] = d;
    s1 += __expf(d);
  }
  for (int i = 32000 + tid; i < 64000; i += 256) row[i] = 0.0f;
  reds[tid] = s1;
  __syncthreads();
  for (int st = 128; st >= 1; st >>= 1) { if (tid < st) reds[tid] += reds[tid + st]; __syncthreads(); }
  if (tid == 0) { s1sh = reds[0]; corrsh = 0.f; }
  __syncthreads();
  if (tid < 200) {
    int v = xv[tid];
    bool own = true;
    for (int s2 = 0; s2 < tid; ++s2) if (xv[s2] == v) { own = false; break; }
    if (own) {
      float delta = 0.f;
      for (int s2 = tid; s2 < 200; ++s2)
        if (xv[s2] == v) delta += ws[OFF_AS + (size_t)r * 200 + s2];
      delta *= (1.0f - pg);
      float base = row[v];
      row[v] = base + delta;
      atomicAdd(&corrsh, __expf(base + delta) - __expf(base));
    }
  }
  __syncthreads();
  if (tid == 0) {
    float lse = logf(s1sh + corrsh + 32000.0f);
    int tgt = labels[b * 51 + tt + 1];
    float dt = row[tgt];
    float valid = (tgt != 0) ? 1.f : 0.f;
    atomicAdd(ws + OFF_ACC + 0, valid * (lse - dt));
    atomicAdd(ws + OFF_ACC + 1, valid);
  }
}

__global__ void k_loss(float* ws, float* out, int out_size) {
  out[out_size - 1] = ws[OFF_ACC + 0] / ws[OFF_ACC + 1] + ws[OFF_ACC + 2] / ws[OFF_ACC + 3];
}

// ---------------- launch ----------------
extern "C" void kernel_launch(void* const* d_in, const int* in_sizes, int n_in,
                              void* d_out, int out_size, void* d_ws, size_t ws_size,
                              hipStream_t stream) {
  (void)in_sizes; (void)n_in; (void)ws_size;
  const int*   x       = (const int*)  d_in[0];
  const int*   labels  = (const int*)  d_in[1];
  const float* emb_enc = (const float*)d_in[3];
  const float* wih_f   = (const float*)d_in[4];
  const float* whh_f   = (const float*)d_in[5];
  const float* bih_f   = (const float*)d_in[6];
  const float* bhh_f   = (const float*)d_in[7];
  const float* wih_b   = (const float*)d_in[8];
  const float* whh_b   = (const float*)d_in[9];
  const float* bih_b   = (const float*)d_in[10];
  const float* bhh_b   = (const float*)d_in[11];
  const float* w_sel1  = (const float*)d_in[12];
  const float* b_sel1  = (const float*)d_in[13];
  const float* w_sel2  = (const float*)d_in[14];
  const float* b_sel2  = (const float*)d_in[15];
  const float* w_rh    = (const float*)d_in[16];
  const float* b_rh    = (const float*)d_in[17];
  const float* w_rc    = (const float*)d_in[18];
  const float* b_rc    = (const float*)d_in[19];
  const float* emb_dec = (const float*)d_in[20];
  const float* wih_d   = (const float*)d_in[21];
  const float* whh_d   = (const float*)d_in[22];
  const float* bih_d   = (const float*)d_in[23];
  const float* bhh_d   = (const float*)d_in[24];
  const float* w_attn  = (const float*)d_in[25];
  const float* b_attn  = (const float*)d_in[26];
  const float* w_attn_v= (const float*)d_in[27];
  const float* w_ptr   = (const float*)d_in[28];
  const float* b_ptr   = (const float*)d_in[29];
  const float* w_gen   = (const float*)d_in[30];
  const float* b_gen   = (const float*)d_in[31];
  const float* w_cov   = (const float*)d_in[32];
  const float* b_cov   = (const float*)d_in[33];
  float* ws  = (float*)d_ws;
  float* out = (float*)d_out;

  hipMemsetAsync(d_ws, 0, ZERO_FLOATS * 4, stream);
  k_biassum<<<12, 256, 0, stream>>>(bih_f, bhh_f, bih_b, bhh_b, bih_d, bhh_d, ws);
  k_embed<<<2000, 256, 0, stream>>>(x, labels, emb_enc, emb_dec, ws);
  k_gemm<64,64,4,4,0,0,0><<<dim3(25,16), 256, 0, stream>>>(ws+OFF_EMB,  wih_f, ws+OFF_BIAS,      ws+OFF_PREF, 1600, 256, 256, 1024);
  k_gemm<64,64,4,4,0,0,1><<<dim3(25,16), 256, 0, stream>>>(ws+OFF_EMB,  wih_b, ws+OFF_BIAS+1024, ws+OFF_PREB, 1600, 256, 256, 1024);
  k_gemm<64,64,4,4,0,0,0><<<dim3(7,16),  256, 0, stream>>>(ws+OFF_DEMB, wih_d, ws+OFF_BIAS+2048, ws+OFF_DPRE, 400,  256, 768, 1024);
  // Clear the gen-tagged h exchange buffer (kills stale tags across graph
  // replays). Must come after the two ih-GEMMs that read OFF_EMB.
  hipMemsetAsync((void*)(ws + OFF_HP), 0, (size_t)2 * 2 * 2048 * sizeof(unsigned long long), stream);
  k_encoder<<<32, 512, 0, stream>>>(whh_f, whh_b, ws);
  k_gemm<64,64,4,4,0,1,0><<<dim3(25,4),  256, 0, stream>>>(ws+OFF_ENCOUT, w_sel1, b_sel1, ws+OFF_HSEL, 1600, 512, 512, 256);
  k_selbce<<<1600, 64, 0, stream>>>(w_sel2, b_sel2, x, ws);
  k_gemm<64,64,4,4,0,0,0><<<dim3(25,4),  256, 0, stream>>>(ws+OFF_ENCOUT, w_attn, b_attn, ws+OFF_EP, 1600, 512, 1024, 256);
  k_wcp<<<1, 256, 0, stream>>>(w_attn, w_cov, b_cov, ws);
  k_h0c0<<<8, 256, 0, stream>>>(w_rh, b_rh, w_rc, b_rc, ws);
  k_decoder<<<32, 512, 0, stream>>>(wih_d, whh_d, w_attn, w_attn_v, ws);
  k_pgen<<<400, 64, 0, stream>>>(w_ptr, b_ptr, ws);
  k_gemm<128,128,8,8,1,0,0><<<dim3(4,250), 256, 0, stream>>>(ws+OFF_HS, w_gen, b_gen, out, 400, 256, 256, 64000);
  k_v2<<<400, 256, 0, stream>>>(x, labels, ws, out);
  k_loss<<<1, 1, 0, stream>>>(ws, out, out_size);
}